// Round 2
// baseline (430.077 us; speedup 1.0000x reference)
//
#include <hip/hip_runtime.h>
#include <math.h>

#define HW   4096
#define CINP 512
#define LCH  64

typedef short bf8 __attribute__((ext_vector_type(8)));   // 8 bf16 = 4 VGPRs
typedef float f4  __attribute__((ext_vector_type(4)));   // MFMA C/D frag

__device__ __forceinline__ unsigned short f2bf(float x) {
    union { float f; unsigned int u; } v; v.f = x;
    return (unsigned short)((v.u + 0x7fffu + ((v.u >> 16) & 1u)) >> 16);
}
__device__ __forceinline__ bf8 ldbf8(const unsigned short* p) {
    uint4 u = *(const uint4*)p;
    return __builtin_bit_cast(bf8, u);
}

// -------------------------------------------------------------------------
// precast: weights (+gain) and concepts to bf16, concepts also transposed.
// WB[192][512] = [wt;wp;wg]*gain   WO[512][64]   CK[256][64]   CV[64][256]
// -------------------------------------------------------------------------
__global__ __launch_bounds__(256) void precast(
    const float* __restrict__ wt, const float* __restrict__ wp,
    const float* __restrict__ wg, const float* __restrict__ wo,
    const float* __restrict__ conc,
    unsigned short* __restrict__ WB, unsigned short* __restrict__ WO,
    unsigned short* __restrict__ CK, unsigned short* __restrict__ CV)
{
    const float gain = 0.04419417382415922f;  // 1/sqrt(512)
    int id = blockIdx.x * 256 + threadIdx.x;
    if (id < 98304) {
        int o = id >> 9, k = id & 511;
        const float* w = (o < 64) ? wt : (o < 128) ? wp : wg;
        WB[id] = f2bf(w[(o & 63) * 512 + k] * gain);
    } else if (id < 131072) {
        int j = id - 98304;
        WO[j] = f2bf(wo[j]);
    } else if (id < 147456) {
        int j = id - 131072;
        CK[j] = f2bf(conc[j]);
    } else if (id < 163840) {
        int j = id - 147456;
        int l = j >> 8, m = j & 255;
        CV[j] = f2bf(conc[m * 64 + l]);
    }
}

// -------------------------------------------------------------------------
// cast_transpose: f fp32 [b][512][4096] -> XT bf16 [b][4096][512]
// -------------------------------------------------------------------------
__global__ __launch_bounds__(256) void cast_transpose(const float* __restrict__ x,
                                                      unsigned short* __restrict__ XT)
{
    __shared__ unsigned short Lb[64][72];   // [n][c]
    const int t  = threadIdx.x;
    const int n0 = blockIdx.x * 64, c0 = blockIdx.y * 64, b = blockIdx.z;
    const float* xb = x + ((size_t)b * CINP + c0) * HW + n0;
    const int cc = t >> 4, n4 = (t & 15) * 4;
    #pragma unroll
    for (int i = 0; i < 4; i++) {
        int c = cc + i * 16;
        float4 v = *(const float4*)(xb + (size_t)c * HW + n4);
        Lb[n4 + 0][c] = f2bf(v.x);
        Lb[n4 + 1][c] = f2bf(v.y);
        Lb[n4 + 2][c] = f2bf(v.z);
        Lb[n4 + 3][c] = f2bf(v.w);
    }
    __syncthreads();
    const int n = t & 63, cb0 = t >> 6;
    unsigned short* orow = XT + ((size_t)b * HW + n0 + n) * CINP + c0;
    #pragma unroll
    for (int i = 0; i < 2; i++) {
        int cb = cb0 + i * 4;
        *(uint4*)(orow + cb * 8) = *(const uint4*)&Lb[n][cb * 8];
    }
}

// -------------------------------------------------------------------------
// lat_transpose: A bf16 flat [b][4096][64] viewed as lat[b][64][4096]
// (raw reinterpret, the torch .view) -> LT[b][4096][64] with LT[b][s][c] =
// lat[b][c][s] = Aflat[b*262144 + c*4096 + s].  64x64 LDS tile.
// -------------------------------------------------------------------------
__global__ __launch_bounds__(256) void lat_transpose(const unsigned short* __restrict__ A,
                                                     unsigned short* __restrict__ LT)
{
    __shared__ unsigned short Ls[64][72];
    const int t = threadIdx.x, s0 = blockIdx.x * 64, b = blockIdx.y;
    const unsigned short* ab = A + (size_t)b * LCH * HW;
    #pragma unroll
    for (int it = 0; it < 2; it++) {
        int c = (t >> 3) + it * 32, s8 = (t & 7) * 8;
        union { uint4 u; unsigned short s[8]; } v;
        v.u = *(const uint4*)(ab + (size_t)c * HW + s0 + s8);
        #pragma unroll
        for (int i = 0; i < 8; i++) Ls[s8 + i][c] = v.s[i];
    }
    __syncthreads();
    unsigned short* ob = LT + ((size_t)b * HW + s0) * LCH;
    #pragma unroll
    for (int it = 0; it < 2; it++) {
        int s = (t >> 3) + it * 32, c8 = (t & 7);
        *(uint4*)(ob + (size_t)s * LCH + c8 * 8) = *(const uint4*)&Ls[s][c8 * 8];
    }
}

// -------------------------------------------------------------------------
// qkv_gemm<NRT>: barrier-free, LDS-free; A (weights) and B (XT rows) frags
// direct from global. NRT=12: Q -> XT cols [0,64), K -> [64,128), V -> VL.
// NRT=4: enc -> XT cols [0,64).
// -------------------------------------------------------------------------
template <int NRT>
__global__ __launch_bounds__(256) void qkv_gemm(unsigned short* XT,
                                                const unsigned short* __restrict__ WB,
                                                unsigned short* __restrict__ VL)
{
    const int t = threadIdx.x;
    const int wave = t >> 6, lane = t & 63, quad = lane >> 4, lidx = lane & 15;
    const int b = blockIdx.y;
    const int ncol = blockIdx.x * 64 + wave * 16 + lidx;
    unsigned short* xrow = XT + ((size_t)b * HW + ncol) * CINP;

    f4 acc[NRT];
    #pragma unroll
    for (int r = 0; r < NRT; r++) acc[r] = (f4){0.f, 0.f, 0.f, 0.f};

    for (int kk = 0; kk < 16; kk++) {
        const int k0 = kk * 32 + quad * 8;
        bf8 bq = ldbf8(xrow + k0);
        #pragma unroll
        for (int rt = 0; rt < NRT; rt++) {
            bf8 aw = ldbf8(WB + (size_t)(rt * 16 + lidx) * CINP + k0);
            acc[rt] = __builtin_amdgcn_mfma_f32_16x16x32_bf16(aw, bq, acc[rt], 0, 0, 0);
        }
    }

    #pragma unroll
    for (int rt = 0; rt < NRT; rt++) {
        if (rt < 8) {  // Q (rt<4) and K (rt<8): n-major, in place in XT
            union { unsigned short s[4]; uint2 u; } pk;
            #pragma unroll
            for (int r = 0; r < 4; r++) pk.s[r] = f2bf(acc[rt][r]);
            int off = (rt < 4) ? (rt * 16 + quad * 4) : (64 + (rt - 4) * 16 + quad * 4);
            *(uint2*)(xrow + off) = pk.u;
        } else {       // V: l-major
            #pragma unroll
            for (int r = 0; r < 4; r++) {
                int l = (rt - 8) * 16 + quad * 4 + r;
                VL[((size_t)b * LCH + l) * HW + ncol] = f2bf(acc[rt][r]);
            }
        }
    }
}

// -------------------------------------------------------------------------
// flash: split-K, max-free-softmax MFMA attention.
// 4 waves per block; each wave does 1/4 of the key tiles for the SAME 32
// queries. Cross-wave combine is a plain LDS sum (2 barriers total).
//
// XCD batch-affinity swizzle: 1-D grid, b = blockIdx.x & 7. HW round-robins
// block id % 8 across the 8 XCDs, so ALL blocks of batch b land on XCD b.
// Per-XCD working set = one batch's K+V+Q (~2 MB) -> L2-resident, instead of
// 8 batches (8 MB) thrashing the 4 MB L2 and bottlenecking on L3 latency*MLP.
// -------------------------------------------------------------------------
__global__ __launch_bounds__(256) void flash(
    const unsigned short* Qb, size_t qbat,
    const unsigned short* Kb, size_t krow, size_t kbat,
    const unsigned short* Vb, size_t vrow, size_t vbat,
    unsigned short* __restrict__ Aout, int nkeys)
{
    // Union: per-wave double-buffered Ps (4 waves x 5120 B = 20480 B) is dead
    // after the K-loop; reuse the space for the cross-wave reduction buffer
    // Red[3][64][41] f32 = 31488 B (41 pad -> odd stride -> conflict-free).
    __shared__ __align__(16) char smem[31488];

    const int t = threadIdx.x;
    const int wave = t >> 6, lane = t & 63, quad = lane >> 4, lidx = lane & 15;
    const int b = blockIdx.x & 7, q0 = (blockIdx.x >> 3) * 32;

    unsigned short (*Ps)[32][40] = (unsigned short (*)[32][40])(smem + wave * 5120);
    float (*Red)[64][41] = (float (*)[64][41])smem;

    const unsigned short* qp = Qb + (size_t)b * qbat;
    const unsigned short* kp = Kb + (size_t)b * kbat;
    const unsigned short* vp = Vb + (size_t)b * vbat;

    bf8 qa[2][2];
    #pragma unroll
    for (int qb = 0; qb < 2; qb++)
        #pragma unroll
        for (int kh = 0; kh < 2; kh++)
            qa[qb][kh] = ldbf8(qp + (size_t)(q0 + qb * 16 + lidx) * CINP + kh * 32 + quad * 8);

    f4 O[2][4];
    float Lp[2][4];
    #pragma unroll
    for (int qb = 0; qb < 2; qb++) {
        #pragma unroll
        for (int lt = 0; lt < 4; lt++) O[qb][lt] = (f4){0.f, 0.f, 0.f, 0.f};
        #pragma unroll
        for (int r = 0; r < 4; r++) Lp[qb][r] = 0.f;
    }

    const int tpw = nkeys >> 7;         // (nkeys/32) tiles / 4 waves
    const int tbase = wave * tpw;
    #pragma unroll 2
    for (int tt = 0; tt < tpw; tt++) {
        const int m0 = (tbase + tt) * 32;
        const unsigned short* kr0 = kp + (size_t)(m0 + lidx) * krow + quad * 8;
        const unsigned short* kr1 = kp + (size_t)(m0 + 16 + lidx) * krow + quad * 8;
        bf8 kf00 = ldbf8(kr0), kf01 = ldbf8(kr0 + 32);
        bf8 kf10 = ldbf8(kr1), kf11 = ldbf8(kr1 + 32);

        f4 S[2][2];
        #pragma unroll
        for (int qb = 0; qb < 2; qb++) {
            S[qb][0] = (f4){0.f, 0.f, 0.f, 0.f};
            S[qb][1] = (f4){0.f, 0.f, 0.f, 0.f};
            S[qb][0] = __builtin_amdgcn_mfma_f32_16x16x32_bf16(qa[qb][0], kf00, S[qb][0], 0, 0, 0);
            S[qb][0] = __builtin_amdgcn_mfma_f32_16x16x32_bf16(qa[qb][1], kf01, S[qb][0], 0, 0, 0);
            S[qb][1] = __builtin_amdgcn_mfma_f32_16x16x32_bf16(qa[qb][0], kf10, S[qb][1], 0, 0, 0);
            S[qb][1] = __builtin_amdgcn_mfma_f32_16x16x32_bf16(qa[qb][1], kf11, S[qb][1], 0, 0, 0);
        }

        // P = exp(S) (scores bounded ~|50| -> no max subtraction needed)
        const int pb = tt & 1;
        #pragma unroll
        for (int qb = 0; qb < 2; qb++)
            #pragma unroll
            for (int ms = 0; ms < 2; ms++)
                #pragma unroll
                for (int r = 0; r < 4; r++) {
                    float p = __expf(S[qb][ms][r]);
                    Lp[qb][r] += p;
                    Ps[pb][qb * 16 + quad * 4 + r][ms * 16 + lidx] = f2bf(p);
                }

        bf8 pf0 = *(const bf8*)&Ps[pb][lidx][quad * 8];
        bf8 pf1 = *(const bf8*)&Ps[pb][16 + lidx][quad * 8];

        #pragma unroll
        for (int lt = 0; lt < 4; lt++) {
            bf8 vf = ldbf8(vp + (size_t)(lt * 16 + lidx) * vrow + m0 + quad * 8);
            O[0][lt] = __builtin_amdgcn_mfma_f32_16x16x32_bf16(pf0, vf, O[0][lt], 0, 0, 0);
            O[1][lt] = __builtin_amdgcn_mfma_f32_16x16x32_bf16(pf1, vf, O[1][lt], 0, 0, 0);
        }
    }

    // ---- cross-wave combine: O and Lp are linear partial sums ----
    __syncthreads();            // all waves done reading their Ps (aliased below)
    if (wave) {
        float* rp = Red[wave - 1][lane];
        int j = 0;
        #pragma unroll
        for (int qb = 0; qb < 2; qb++)
            #pragma unroll
            for (int lt = 0; lt < 4; lt++)
                #pragma unroll
                for (int r = 0; r < 4; r++) rp[j++] = O[qb][lt][r];
        #pragma unroll
        for (int qb = 0; qb < 2; qb++)
            #pragma unroll
            for (int r = 0; r < 4; r++) rp[32 + qb * 4 + r] = Lp[qb][r];
    }
    __syncthreads();
    if (wave == 0) {
        #pragma unroll
        for (int w = 0; w < 3; w++) {
            const float* rp = Red[w][lane];
            int j = 0;
            #pragma unroll
            for (int qb = 0; qb < 2; qb++)
                #pragma unroll
                for (int lt = 0; lt < 4; lt++)
                    #pragma unroll
                    for (int r = 0; r < 4; r++) O[qb][lt][r] += rp[j++];
            #pragma unroll
            for (int qb = 0; qb < 2; qb++)
                #pragma unroll
                for (int r = 0; r < 4; r++) Lp[qb][r] += rp[32 + qb * 4 + r];
        }

        #pragma unroll
        for (int qb = 0; qb < 2; qb++) {
            float inv[4];
            #pragma unroll
            for (int r = 0; r < 4; r++) {
                float s = Lp[qb][r];
                s += __shfl_xor(s, 1);
                s += __shfl_xor(s, 2);
                s += __shfl_xor(s, 4);
                s += __shfl_xor(s, 8);
                inv[r] = 1.f / s;
            }
            #pragma unroll
            for (int lt = 0; lt < 4; lt++)
                #pragma unroll
                for (int r = 0; r < 4; r++) {
                    size_t n = (size_t)b * HW + q0 + qb * 16 + quad * 4 + r;
                    Aout[n * LCH + lt * 16 + lidx] = f2bf(O[qb][lt][r] * inv[r]);
                }
        }
    }
}

// -------------------------------------------------------------------------
// conv_o: out[b,o,s] = gamma/8 * sum_c WO[o,c]*LT[s,c] + res[b,o,s]
// LT: bf16 [b][4096][64] with LT[s][c] = lat[c][s] (lat_transpose output).
// Optionally emits ST bf16 [b][s][512] (transposed sa_out for stage-2).
// -------------------------------------------------------------------------
__global__ __launch_bounds__(256) void conv_o(const unsigned short* __restrict__ LT,
                                              const unsigned short* __restrict__ WO,
                                              const float* __restrict__ res,
                                              const float* __restrict__ gamma_p,
                                              float* __restrict__ out,
                                              unsigned short* ST)
{
    const int t = threadIdx.x;
    const int wave = t >> 6, lane = t & 63, quad = lane >> 4, lidx = lane & 15;
    const int b = blockIdx.z, o0 = blockIdx.y * 64;
    const int scol = blockIdx.x * 64 + wave * 16 + lidx;
    const unsigned short* arow = LT + ((size_t)b * HW + scol) * LCH;

    f4 acc[4];
    #pragma unroll
    for (int ot = 0; ot < 4; ot++) acc[ot] = (f4){0.f, 0.f, 0.f, 0.f};

    #pragma unroll
    for (int kh = 0; kh < 2; kh++) {
        bf8 bq = ldbf8(arow + kh * 32 + quad * 8);
        #pragma unroll
        for (int ot = 0; ot < 4; ot++) {
            bf8 af = ldbf8(WO + (size_t)(o0 + ot * 16 + lidx) * LCH + kh * 32 + quad * 8);
            acc[ot] = __builtin_amdgcn_mfma_f32_16x16x32_bf16(af, bq, acc[ot], 0, 0, 0);
        }
    }

    const float scale = gamma_p[0] * 0.125f;  // gamma * 1/sqrt(64)
    #pragma unroll
    for (int ot = 0; ot < 4; ot++) {
        float v[4];
        #pragma unroll
        for (int r = 0; r < 4; r++) {
            size_t idx = ((size_t)b * CINP + o0 + ot * 16 + quad * 4 + r) * HW + scol;
            v[r] = fmaf(scale, acc[ot][r], res[idx]);
            out[idx] = v[r];
        }
        if (ST) {
            union { unsigned short s[4]; uint2 u; } pk;
            #pragma unroll
            for (int r = 0; r < 4; r++) pk.s[r] = f2bf(v[r]);
            *(uint2*)(ST + ((size_t)b * HW + scol) * CINP + o0 + ot * 16 + quad * 4) = pk.u;
        }
    }
}

// -------------------------------------------------------------------------
extern "C" void kernel_launch(void* const* d_in, const int* in_sizes, int n_in,
                              void* d_out, int out_size, void* d_ws, size_t ws_size,
                              hipStream_t stream)
{
    const float* f    = (const float*)d_in[0];
    const float* conc = (const float*)d_in[1];
    const float* wt   = (const float*)d_in[2];
    const float* wp   = (const float*)d_in[3];
    const float* wg   = (const float*)d_in[4];
    const float* wo   = (const float*)d_in[5];
    const float* gsa  = (const float*)d_in[6];
    const float* gmo  = (const float*)d_in[7];
    float* out = (float*)d_out;

    // ws layout (~40.4 MiB):
    //  [0, 32M)   XT bf16 [8][4096][512]; Q/K in place -> later ST + Q2 in place
    //  [32M,36M)  VL bf16 [8][64][4096]  -> later LT (lat transposed)
    //  [36M,40M)  A1/A2 bf16 [8][4096][64] (attention out, n-major)
    //  [40M,...)  WB WO CK CV bf16
    char* ws = (char*)d_ws;
    unsigned short* XT = (unsigned short*)ws;
    unsigned short* VL = (unsigned short*)(ws + ((size_t)32 << 20));
    unsigned short* LT = VL;  // reuse after flash1
    unsigned short* A1 = (unsigned short*)(ws + ((size_t)36 << 20));
    unsigned short* WB = (unsigned short*)(ws + ((size_t)40 << 20));
    unsigned short* WO = WB + 192 * 512;
    unsigned short* CK = WO + 512 * 64;
    unsigned short* CV = CK + 256 * 64;

    dim3 blk256(256);

    precast<<<640, blk256, 0, stream>>>(wt, wp, wg, wo, conc, WB, WO, CK, CV);
    cast_transpose<<<dim3(64, 8, 8), blk256, 0, stream>>>(f, XT);

    // ---- SelfAttention ----
    qkv_gemm<12><<<dim3(64, 8), blk256, 0, stream>>>(XT, WB, VL);
    flash<<<dim3(1024), blk256, 0, stream>>>(
        XT, (size_t)HW * CINP,
        XT + 64, CINP, (size_t)HW * CINP,
        VL, HW, (size_t)LCH * HW,
        A1, HW);
    lat_transpose<<<dim3(64, 8), blk256, 0, stream>>>(A1, LT);
    conv_o<<<dim3(64, 8, 8), blk256, 0, stream>>>(LT, WO, f, gsa, out, XT /*emit ST*/);

    // ---- MomentumConceptAttention ----
    qkv_gemm<4><<<dim3(64, 8), blk256, 0, stream>>>(XT /*=ST*/, WB /*wt rows*/, nullptr);
    flash<<<dim3(1024), blk256, 0, stream>>>(
        XT, (size_t)HW * CINP,
        CK, LCH, 0,
        CV, 256, 0,
        A1 /*=A2*/, 256);
    lat_transpose<<<dim3(64, 8), blk256, 0, stream>>>(A1, LT);
    conv_o<<<dim3(64, 8, 8), blk256, 0, stream>>>(LT, WO, out, gmo, out, nullptr);
}

// Round 3
// 397.235 us; speedup vs baseline: 1.0827x; 1.0827x over previous
//
#include <hip/hip_runtime.h>
#include <math.h>

#define HW   4096
#define CINP 512
#define LCH  64

typedef short bf8 __attribute__((ext_vector_type(8)));   // 8 bf16 = 4 VGPRs
typedef float f4  __attribute__((ext_vector_type(4)));   // MFMA C/D frag

__device__ __forceinline__ unsigned short f2bf(float x) {
    union { float f; unsigned int u; } v; v.f = x;
    return (unsigned short)((v.u + 0x7fffu + ((v.u >> 16) & 1u)) >> 16);
}
__device__ __forceinline__ bf8 ldbf8(const unsigned short* p) {
    uint4 u = *(const uint4*)p;
    return __builtin_bit_cast(bf8, u);
}
// pack two f32 -> two bf16 (RNE), dst.lo = a, dst.hi = b
__device__ __forceinline__ unsigned int cvtpk(float a, float b) {
    unsigned int r;
    asm volatile("v_cvt_pk_bf16_f32 %0, %1, %2" : "=v"(r) : "v"(a), "v"(b));
    return r;
}

// -------------------------------------------------------------------------
// precast: weights (+gain) and concepts to bf16, concepts also transposed.
// WB[192][512] = [wt;wp;wg]*gain   WO[512][64]   CK[256][64]   CV[64][256]
// -------------------------------------------------------------------------
__global__ __launch_bounds__(256) void precast(
    const float* __restrict__ wt, const float* __restrict__ wp,
    const float* __restrict__ wg, const float* __restrict__ wo,
    const float* __restrict__ conc,
    unsigned short* __restrict__ WB, unsigned short* __restrict__ WO,
    unsigned short* __restrict__ CK, unsigned short* __restrict__ CV)
{
    const float gain = 0.04419417382415922f;  // 1/sqrt(512)
    int id = blockIdx.x * 256 + threadIdx.x;
    if (id < 98304) {
        int o = id >> 9, k = id & 511;
        const float* w = (o < 64) ? wt : (o < 128) ? wp : wg;
        WB[id] = f2bf(w[(o & 63) * 512 + k] * gain);
    } else if (id < 131072) {
        int j = id - 98304;
        WO[j] = f2bf(wo[j]);
    } else if (id < 147456) {
        int j = id - 131072;
        CK[j] = f2bf(conc[j]);
    } else if (id < 163840) {
        int j = id - 147456;
        int l = j >> 8, m = j & 255;
        CV[j] = f2bf(conc[m * 64 + l]);
    }
}

// -------------------------------------------------------------------------
// cast_transpose: f fp32 [b][512][4096] -> XT bf16 [b][4096][512]
// -------------------------------------------------------------------------
__global__ __launch_bounds__(256) void cast_transpose(const float* __restrict__ x,
                                                      unsigned short* __restrict__ XT)
{
    __shared__ unsigned short Lb[64][72];   // [n][c]
    const int t  = threadIdx.x;
    const int n0 = blockIdx.x * 64, c0 = blockIdx.y * 64, b = blockIdx.z;
    const float* xb = x + ((size_t)b * CINP + c0) * HW + n0;
    const int cc = t >> 4, n4 = (t & 15) * 4;
    #pragma unroll
    for (int i = 0; i < 4; i++) {
        int c = cc + i * 16;
        float4 v = *(const float4*)(xb + (size_t)c * HW + n4);
        Lb[n4 + 0][c] = f2bf(v.x);
        Lb[n4 + 1][c] = f2bf(v.y);
        Lb[n4 + 2][c] = f2bf(v.z);
        Lb[n4 + 3][c] = f2bf(v.w);
    }
    __syncthreads();
    const int n = t & 63, cb0 = t >> 6;
    unsigned short* orow = XT + ((size_t)b * HW + n0 + n) * CINP + c0;
    #pragma unroll
    for (int i = 0; i < 2; i++) {
        int cb = cb0 + i * 4;
        *(uint4*)(orow + cb * 8) = *(const uint4*)&Lb[n][cb * 8];
    }
}

// -------------------------------------------------------------------------
// lat_transpose: A bf16 flat [b][4096][64] viewed as lat[b][64][4096]
// (raw reinterpret, the torch .view) -> LT[b][4096][64] with LT[b][s][c] =
// lat[b][c][s] = Aflat[b*262144 + c*4096 + s].  64x64 LDS tile.
// -------------------------------------------------------------------------
__global__ __launch_bounds__(256) void lat_transpose(const unsigned short* __restrict__ A,
                                                     unsigned short* __restrict__ LT)
{
    __shared__ unsigned short Ls[64][72];
    const int t = threadIdx.x, s0 = blockIdx.x * 64, b = blockIdx.y;
    const unsigned short* ab = A + (size_t)b * LCH * HW;
    #pragma unroll
    for (int it = 0; it < 2; it++) {
        int c = (t >> 3) + it * 32, s8 = (t & 7) * 8;
        union { uint4 u; unsigned short s[8]; } v;
        v.u = *(const uint4*)(ab + (size_t)c * HW + s0 + s8);
        #pragma unroll
        for (int i = 0; i < 8; i++) Ls[s8 + i][c] = v.s[i];
    }
    __syncthreads();
    unsigned short* ob = LT + ((size_t)b * HW + s0) * LCH;
    #pragma unroll
    for (int it = 0; it < 2; it++) {
        int s = (t >> 3) + it * 32, c8 = (t & 7);
        *(uint4*)(ob + (size_t)s * LCH + c8 * 8) = *(const uint4*)&Ls[s][c8 * 8];
    }
}

// -------------------------------------------------------------------------
// qkv_gemm<NRT>: barrier-free, LDS-free; A (weights) and B (XT rows) frags
// direct from global. NRT=12: Q -> XT cols [0,64), K -> [64,128), V -> VL.
// NRT=4: enc -> XT cols [0,64).
// -------------------------------------------------------------------------
template <int NRT>
__global__ __launch_bounds__(256) void qkv_gemm(unsigned short* XT,
                                                const unsigned short* __restrict__ WB,
                                                unsigned short* __restrict__ VL)
{
    const int t = threadIdx.x;
    const int wave = t >> 6, lane = t & 63, quad = lane >> 4, lidx = lane & 15;
    const int b = blockIdx.y;
    const int ncol = blockIdx.x * 64 + wave * 16 + lidx;
    unsigned short* xrow = XT + ((size_t)b * HW + ncol) * CINP;

    f4 acc[NRT];
    #pragma unroll
    for (int r = 0; r < NRT; r++) acc[r] = (f4){0.f, 0.f, 0.f, 0.f};

    for (int kk = 0; kk < 16; kk++) {
        const int k0 = kk * 32 + quad * 8;
        bf8 bq = ldbf8(xrow + k0);
        #pragma unroll
        for (int rt = 0; rt < NRT; rt++) {
            bf8 aw = ldbf8(WB + (size_t)(rt * 16 + lidx) * CINP + k0);
            acc[rt] = __builtin_amdgcn_mfma_f32_16x16x32_bf16(aw, bq, acc[rt], 0, 0, 0);
        }
    }

    #pragma unroll
    for (int rt = 0; rt < NRT; rt++) {
        if (rt < 8) {  // Q (rt<4) and K (rt<8): n-major, in place in XT
            union { unsigned short s[4]; uint2 u; } pk;
            #pragma unroll
            for (int r = 0; r < 4; r++) pk.s[r] = f2bf(acc[rt][r]);
            int off = (rt < 4) ? (rt * 16 + quad * 4) : (64 + (rt - 4) * 16 + quad * 4);
            *(uint2*)(xrow + off) = pk.u;
        } else {       // V: l-major
            #pragma unroll
            for (int r = 0; r < 4; r++) {
                int l = (rt - 8) * 16 + quad * 4 + r;
                VL[((size_t)b * LCH + l) * HW + ncol] = f2bf(acc[rt][r]);
            }
        }
    }
}

// -------------------------------------------------------------------------
// flash: split-Q, cooperative-LDS-staging, max-free-softmax MFMA attention.
// Block = 4 waves x 32 queries = 128 queries. The block loops over ALL key
// tiles (32 keys each); K-tile and V-tile are staged ONCE per block into LDS
// with coalesced dwordx4 loads (double-buffered, prefetch issued at the top
// of the iteration), then consumed by all 4 waves -> ~6x fewer cache-line
// requests vs per-wave scattered global loads (the measured TA-pipe wall).
//
// QK^T computed with SWAPPED operands: S = mfma(K,Q) -> D[key][query], so
// each lane holds 4 consecutive keys of one query -> P packed with
// v_cvt_pk_bf16_f32 and stored as one ds_write_b64 (replaces 16 b16 writes).
// Out: bf16 [b][4096][64] (n-major).
// -------------------------------------------------------------------------
__global__ __launch_bounds__(256) void flash(
    const unsigned short* Qb, size_t qbat,
    const unsigned short* Kb, size_t krow, size_t kbat,
    const unsigned short* Vb, size_t vrow, size_t vbat,
    unsigned short* __restrict__ Aout, int nkeys)
{
    __shared__ __align__(16) unsigned short Ks[2][32][72];  // [buf][key][ch]   (pad 64->72)
    __shared__ __align__(16) unsigned short Vs[2][64][40];  // [buf][l][key]    (pad 32->40)
    __shared__ __align__(16) unsigned short Ps[4][32][40];  // [wave][query][key] (pad 32->40)

    const int t = threadIdx.x;
    const int wave = t >> 6, lane = t & 63, quad = lane >> 4, lidx = lane & 15;
    const int b = blockIdx.y, q0 = blockIdx.x * 128 + wave * 32;

    const unsigned short* qp = Qb + (size_t)b * qbat;
    const unsigned short* kp = Kb + (size_t)b * kbat;
    const unsigned short* vp = Vb + (size_t)b * vbat;

    // staging roles: K: 32 rows x 8 chunks(16B); V: 64 rows x 4 chunks(16B)
    const int krt = t >> 3, kch = (t & 7) * 8;
    const int vrt = t >> 2, vch = (t & 3) * 8;

    // Q fragments (B-operand of swapped QK): Q[query qb*16+lidx][ch kh*32+quad*8]
    bf8 qa[2][2];
    #pragma unroll
    for (int qb = 0; qb < 2; qb++)
        #pragma unroll
        for (int kh = 0; kh < 2; kh++)
            qa[qb][kh] = ldbf8(qp + (size_t)(q0 + qb * 16 + lidx) * CINP + kh * 32 + quad * 8);

    f4 O[2][4];
    float Lp[2] = {0.f, 0.f};
    #pragma unroll
    for (int qb = 0; qb < 2; qb++)
        #pragma unroll
        for (int lt = 0; lt < 4; lt++) O[qb][lt] = (f4){0.f, 0.f, 0.f, 0.f};

    const int nt = nkeys >> 5;

    // prologue: stage tile 0 into buf 0
    {
        uint4 k0v = *(const uint4*)(kp + (size_t)krt * krow + kch);
        uint4 v0v = *(const uint4*)(vp + (size_t)vrt * vrow + vch);
        *(uint4*)&Ks[0][krt][kch] = k0v;
        *(uint4*)&Vs[0][vrt][vch] = v0v;
    }
    __syncthreads();

    for (int tl = 0; tl < nt; tl++) {
        const int cur = tl & 1;
        const bool pf = (tl + 1 < nt);
        uint4 kpre, vpre;
        if (pf) {  // issue next-tile global loads early; consumed after compute
            const int m1 = (tl + 1) * 32;
            kpre = *(const uint4*)(kp + (size_t)(m1 + krt) * krow + kch);
            vpre = *(const uint4*)(vp + (size_t)vrt * vrow + m1 + vch);
        }

        // K frags (A-operand): K[key ms*16+lidx][ch kh*32+quad*8]
        bf8 kf[2][2];
        #pragma unroll
        for (int ms = 0; ms < 2; ms++)
            #pragma unroll
            for (int kh = 0; kh < 2; kh++)
                kf[ms][kh] = *(const bf8*)&Ks[cur][ms * 16 + lidx][kh * 32 + quad * 8];

        // S = K . Q^T : D[key quad*4+r (+ms*16)][query lidx (+qb*16)]
        f4 S[2][2];
        #pragma unroll
        for (int qb = 0; qb < 2; qb++)
            #pragma unroll
            for (int ms = 0; ms < 2; ms++) {
                f4 s = (f4){0.f, 0.f, 0.f, 0.f};
                s = __builtin_amdgcn_mfma_f32_16x16x32_bf16(kf[ms][0], qa[qb][0], s, 0, 0, 0);
                s = __builtin_amdgcn_mfma_f32_16x16x32_bf16(kf[ms][1], qa[qb][1], s, 0, 0, 0);
                S[qb][ms] = s;
            }

        // P = exp(S) (scores bounded ~|50| -> no max subtraction needed);
        // lane holds 4 consecutive keys -> pack & one b64 write per (qb,ms)
        #pragma unroll
        for (int qb = 0; qb < 2; qb++)
            #pragma unroll
            for (int ms = 0; ms < 2; ms++) {
                float p0 = __expf(S[qb][ms][0]);
                float p1 = __expf(S[qb][ms][1]);
                float p2 = __expf(S[qb][ms][2]);
                float p3 = __expf(S[qb][ms][3]);
                Lp[qb] += (p0 + p1) + (p2 + p3);
                uint2 pk;
                pk.x = cvtpk(p0, p1);
                pk.y = cvtpk(p2, p3);
                *(uint2*)&Ps[wave][qb * 16 + lidx][ms * 16 + quad * 4] = pk;
            }

        // PV: A = P[query][key], B = V[l][key]
        bf8 pf0 = *(const bf8*)&Ps[wave][lidx][quad * 8];
        bf8 pf1 = *(const bf8*)&Ps[wave][16 + lidx][quad * 8];
        #pragma unroll
        for (int lt = 0; lt < 4; lt++) {
            bf8 vf = *(const bf8*)&Vs[cur][lt * 16 + lidx][quad * 8];
            O[0][lt] = __builtin_amdgcn_mfma_f32_16x16x32_bf16(pf0, vf, O[0][lt], 0, 0, 0);
            O[1][lt] = __builtin_amdgcn_mfma_f32_16x16x32_bf16(pf1, vf, O[1][lt], 0, 0, 0);
        }

        if (pf) {  // write prefetched tile into the other buffer
            *(uint4*)&Ks[cur ^ 1][krt][kch] = kpre;
            *(uint4*)&Vs[cur ^ 1][vrt][vch] = vpre;
        }
        __syncthreads();
    }

    // ---- normalize & write: L[query] lives at lane lidx=query (cross-quad sum) ----
    float inv[2];
    #pragma unroll
    for (int qb = 0; qb < 2; qb++) {
        float s = Lp[qb];
        s += __shfl_xor(s, 16);
        s += __shfl_xor(s, 32);
        inv[qb] = 1.f / s;
    }
    #pragma unroll
    for (int qb = 0; qb < 2; qb++)
        #pragma unroll
        for (int r = 0; r < 4; r++) {
            float iv = __shfl(inv[qb], quad * 4 + r);  // query qb*16+quad*4+r
            size_t n = (size_t)b * HW + q0 + qb * 16 + quad * 4 + r;
            #pragma unroll
            for (int lt = 0; lt < 4; lt++)
                Aout[n * LCH + lt * 16 + lidx] = f2bf(O[qb][lt][r] * iv);
        }
}

// -------------------------------------------------------------------------
// conv_o: out[b,o,s] = gamma/8 * sum_c WO[o,c]*LT[s,c] + res[b,o,s]
// LT: bf16 [b][4096][64] with LT[s][c] = lat[c][s] (lat_transpose output).
// Optionally emits ST bf16 [b][s][512] (transposed sa_out for stage-2).
// -------------------------------------------------------------------------
__global__ __launch_bounds__(256) void conv_o(const unsigned short* __restrict__ LT,
                                              const unsigned short* __restrict__ WO,
                                              const float* __restrict__ res,
                                              const float* __restrict__ gamma_p,
                                              float* __restrict__ out,
                                              unsigned short* ST)
{
    const int t = threadIdx.x;
    const int wave = t >> 6, lane = t & 63, quad = lane >> 4, lidx = lane & 15;
    const int b = blockIdx.z, o0 = blockIdx.y * 64;
    const int scol = blockIdx.x * 64 + wave * 16 + lidx;
    const unsigned short* arow = LT + ((size_t)b * HW + scol) * LCH;

    f4 acc[4];
    #pragma unroll
    for (int ot = 0; ot < 4; ot++) acc[ot] = (f4){0.f, 0.f, 0.f, 0.f};

    #pragma unroll
    for (int kh = 0; kh < 2; kh++) {
        bf8 bq = ldbf8(arow + kh * 32 + quad * 8);
        #pragma unroll
        for (int ot = 0; ot < 4; ot++) {
            bf8 af = ldbf8(WO + (size_t)(o0 + ot * 16 + lidx) * LCH + kh * 32 + quad * 8);
            acc[ot] = __builtin_amdgcn_mfma_f32_16x16x32_bf16(af, bq, acc[ot], 0, 0, 0);
        }
    }

    const float scale = gamma_p[0] * 0.125f;  // gamma * 1/sqrt(64)
    #pragma unroll
    for (int ot = 0; ot < 4; ot++) {
        float v[4];
        #pragma unroll
        for (int r = 0; r < 4; r++) {
            size_t idx = ((size_t)b * CINP + o0 + ot * 16 + quad * 4 + r) * HW + scol;
            v[r] = fmaf(scale, acc[ot][r], res[idx]);
            out[idx] = v[r];
        }
        if (ST) {
            union { unsigned short s[4]; uint2 u; } pk;
            #pragma unroll
            for (int r = 0; r < 4; r++) pk.s[r] = f2bf(v[r]);
            *(uint2*)(ST + ((size_t)b * HW + scol) * CINP + o0 + ot * 16 + quad * 4) = pk.u;
        }
    }
}

// -------------------------------------------------------------------------
extern "C" void kernel_launch(void* const* d_in, const int* in_sizes, int n_in,
                              void* d_out, int out_size, void* d_ws, size_t ws_size,
                              hipStream_t stream)
{
    const float* f    = (const float*)d_in[0];
    const float* conc = (const float*)d_in[1];
    const float* wt   = (const float*)d_in[2];
    const float* wp   = (const float*)d_in[3];
    const float* wg   = (const float*)d_in[4];
    const float* wo   = (const float*)d_in[5];
    const float* gsa  = (const float*)d_in[6];
    const float* gmo  = (const float*)d_in[7];
    float* out = (float*)d_out;

    // ws layout (~40.4 MiB):
    //  [0, 32M)   XT bf16 [8][4096][512]; Q/K in place -> later ST + Q2 in place
    //  [32M,36M)  VL bf16 [8][64][4096]  -> later LT (lat transposed)
    //  [36M,40M)  A1/A2 bf16 [8][4096][64] (attention out, n-major)
    //  [40M,...)  WB WO CK CV bf16
    char* ws = (char*)d_ws;
    unsigned short* XT = (unsigned short*)ws;
    unsigned short* VL = (unsigned short*)(ws + ((size_t)32 << 20));
    unsigned short* LT = VL;  // reuse after flash1
    unsigned short* A1 = (unsigned short*)(ws + ((size_t)36 << 20));
    unsigned short* WB = (unsigned short*)(ws + ((size_t)40 << 20));
    unsigned short* WO = WB + 192 * 512;
    unsigned short* CK = WO + 512 * 64;
    unsigned short* CV = CK + 256 * 64;

    dim3 blk256(256);

    precast<<<640, blk256, 0, stream>>>(wt, wp, wg, wo, conc, WB, WO, CK, CV);
    cast_transpose<<<dim3(64, 8, 8), blk256, 0, stream>>>(f, XT);

    // ---- SelfAttention ----
    qkv_gemm<12><<<dim3(64, 8), blk256, 0, stream>>>(XT, WB, VL);
    flash<<<dim3(32, 8), blk256, 0, stream>>>(
        XT, (size_t)HW * CINP,
        XT + 64, CINP, (size_t)HW * CINP,
        VL, HW, (size_t)LCH * HW,
        A1, HW);
    lat_transpose<<<dim3(64, 8), blk256, 0, stream>>>(A1, LT);
    conv_o<<<dim3(64, 8, 8), blk256, 0, stream>>>(LT, WO, f, gsa, out, XT /*emit ST*/);

    // ---- MomentumConceptAttention ----
    qkv_gemm<4><<<dim3(64, 8), blk256, 0, stream>>>(XT /*=ST*/, WB /*wt rows*/, nullptr);
    flash<<<dim3(32, 8), blk256, 0, stream>>>(
        XT, (size_t)HW * CINP,
        CK, LCH, 0,
        CV, 256, 0,
        A1 /*=A2*/, 256);
    lat_transpose<<<dim3(64, 8), blk256, 0, stream>>>(A1, LT);
    conv_o<<<dim3(64, 8, 8), blk256, 0, stream>>>(LT, WO, out, gmo, out, nullptr);
}

// Round 4
// 393.744 us; speedup vs baseline: 1.0923x; 1.0089x over previous
//
#include <hip/hip_runtime.h>
#include <math.h>

#define HW   4096
#define CINP 512
#define LCH  64

typedef short bf8 __attribute__((ext_vector_type(8)));   // 8 bf16 = 4 VGPRs
typedef float f4  __attribute__((ext_vector_type(4)));   // MFMA C/D frag

__device__ __forceinline__ unsigned short f2bf(float x) {
    union { float f; unsigned int u; } v; v.f = x;
    return (unsigned short)((v.u + 0x7fffu + ((v.u >> 16) & 1u)) >> 16);
}
__device__ __forceinline__ bf8 ldbf8(const unsigned short* p) {
    uint4 u = *(const uint4*)p;
    return __builtin_bit_cast(bf8, u);
}
// pack two f32 -> two bf16 (RNE), dst.lo = a, dst.hi = b
__device__ __forceinline__ unsigned int cvtpk(float a, float b) {
    unsigned int r;
    asm volatile("v_cvt_pk_bf16_f32 %0, %1, %2" : "=v"(r) : "v"(a), "v"(b));
    return r;
}

// -------------------------------------------------------------------------
// precast: weights (+gain) and concepts to bf16, concepts also transposed.
// WB[192][512] = [wt;wp;wg]*gain   WO[512][64]   CK[256][64]   CV[64][256]
// -------------------------------------------------------------------------
__global__ __launch_bounds__(256) void precast(
    const float* __restrict__ wt, const float* __restrict__ wp,
    const float* __restrict__ wg, const float* __restrict__ wo,
    const float* __restrict__ conc,
    unsigned short* __restrict__ WB, unsigned short* __restrict__ WO,
    unsigned short* __restrict__ CK, unsigned short* __restrict__ CV)
{
    const float gain = 0.04419417382415922f;  // 1/sqrt(512)
    int id = blockIdx.x * 256 + threadIdx.x;
    if (id < 98304) {
        int o = id >> 9, k = id & 511;
        const float* w = (o < 64) ? wt : (o < 128) ? wp : wg;
        WB[id] = f2bf(w[(o & 63) * 512 + k] * gain);
    } else if (id < 131072) {
        int j = id - 98304;
        WO[j] = f2bf(wo[j]);
    } else if (id < 147456) {
        int j = id - 131072;
        CK[j] = f2bf(conc[j]);
    } else if (id < 163840) {
        int j = id - 147456;
        int l = j >> 8, m = j & 255;
        CV[j] = f2bf(conc[m * 64 + l]);
    }
}

// -------------------------------------------------------------------------
// cast_transpose: f fp32 [b][512][4096] -> XT bf16 [b][4096][512]
// -------------------------------------------------------------------------
__global__ __launch_bounds__(256) void cast_transpose(const float* __restrict__ x,
                                                      unsigned short* __restrict__ XT)
{
    __shared__ unsigned short Lb[64][72];   // [n][c]
    const int t  = threadIdx.x;
    const int n0 = blockIdx.x * 64, c0 = blockIdx.y * 64, b = blockIdx.z;
    const float* xb = x + ((size_t)b * CINP + c0) * HW + n0;
    const int cc = t >> 4, n4 = (t & 15) * 4;
    #pragma unroll
    for (int i = 0; i < 4; i++) {
        int c = cc + i * 16;
        float4 v = *(const float4*)(xb + (size_t)c * HW + n4);
        Lb[n4 + 0][c] = f2bf(v.x);
        Lb[n4 + 1][c] = f2bf(v.y);
        Lb[n4 + 2][c] = f2bf(v.z);
        Lb[n4 + 3][c] = f2bf(v.w);
    }
    __syncthreads();
    const int n = t & 63, cb0 = t >> 6;
    unsigned short* orow = XT + ((size_t)b * HW + n0 + n) * CINP + c0;
    #pragma unroll
    for (int i = 0; i < 2; i++) {
        int cb = cb0 + i * 4;
        *(uint4*)(orow + cb * 8) = *(const uint4*)&Lb[n][cb * 8];
    }
}

// -------------------------------------------------------------------------
// lat_transpose: A bf16 flat [b][4096][64] viewed as lat[b][64][4096]
// (raw reinterpret, the torch .view) -> LT[b][4096][64] with LT[b][s][c] =
// lat[b][c][s] = Aflat[b*262144 + c*4096 + s].  64x64 LDS tile.
// -------------------------------------------------------------------------
__global__ __launch_bounds__(256) void lat_transpose(const unsigned short* __restrict__ A,
                                                     unsigned short* __restrict__ LT)
{
    __shared__ unsigned short Ls[64][72];
    const int t = threadIdx.x, s0 = blockIdx.x * 64, b = blockIdx.y;
    const unsigned short* ab = A + (size_t)b * LCH * HW;
    #pragma unroll
    for (int it = 0; it < 2; it++) {
        int c = (t >> 3) + it * 32, s8 = (t & 7) * 8;
        union { uint4 u; unsigned short s[8]; } v;
        v.u = *(const uint4*)(ab + (size_t)c * HW + s0 + s8);
        #pragma unroll
        for (int i = 0; i < 8; i++) Ls[s8 + i][c] = v.s[i];
    }
    __syncthreads();
    unsigned short* ob = LT + ((size_t)b * HW + s0) * LCH;
    #pragma unroll
    for (int it = 0; it < 2; it++) {
        int s = (t >> 3) + it * 32, c8 = (t & 7);
        *(uint4*)(ob + (size_t)s * LCH + c8 * 8) = *(const uint4*)&Ls[s][c8 * 8];
    }
}

// -------------------------------------------------------------------------
// qkv_gemm<NRT>: barrier-free, LDS-free; A (weights) and B (XT rows) frags
// direct from global. NRT=12: Q -> XT cols [0,64), K -> [64,128), V -> VL.
// NRT=4: enc -> XT cols [0,64).
// -------------------------------------------------------------------------
template <int NRT>
__global__ __launch_bounds__(256) void qkv_gemm(unsigned short* XT,
                                                const unsigned short* __restrict__ WB,
                                                unsigned short* __restrict__ VL)
{
    const int t = threadIdx.x;
    const int wave = t >> 6, lane = t & 63, quad = lane >> 4, lidx = lane & 15;
    const int b = blockIdx.y;
    const int ncol = blockIdx.x * 64 + wave * 16 + lidx;
    unsigned short* xrow = XT + ((size_t)b * HW + ncol) * CINP;

    f4 acc[NRT];
    #pragma unroll
    for (int r = 0; r < NRT; r++) acc[r] = (f4){0.f, 0.f, 0.f, 0.f};

    for (int kk = 0; kk < 16; kk++) {
        const int k0 = kk * 32 + quad * 8;
        bf8 bq = ldbf8(xrow + k0);
        #pragma unroll
        for (int rt = 0; rt < NRT; rt++) {
            bf8 aw = ldbf8(WB + (size_t)(rt * 16 + lidx) * CINP + k0);
            acc[rt] = __builtin_amdgcn_mfma_f32_16x16x32_bf16(aw, bq, acc[rt], 0, 0, 0);
        }
    }

    #pragma unroll
    for (int rt = 0; rt < NRT; rt++) {
        if (rt < 8) {  // Q (rt<4) and K (rt<8): n-major, in place in XT
            union { unsigned short s[4]; uint2 u; } pk;
            #pragma unroll
            for (int r = 0; r < 4; r++) pk.s[r] = f2bf(acc[rt][r]);
            int off = (rt < 4) ? (rt * 16 + quad * 4) : (64 + (rt - 4) * 16 + quad * 4);
            *(uint2*)(xrow + off) = pk.u;
        } else {       // V: l-major
            #pragma unroll
            for (int r = 0; r < 4; r++) {
                int l = (rt - 8) * 16 + quad * 4 + r;
                VL[((size_t)b * LCH + l) * HW + ncol] = f2bf(acc[rt][r]);
            }
        }
    }
}

// -------------------------------------------------------------------------
// flash: split-Q, cooperative-LDS-staging, max-free-softmax MFMA attention.
// Block = 8 waves x 16 queries = 128 queries (512 threads). The block loops
// over ALL key tiles (32 keys each); K-tile and V-tile are staged ONCE per
// block into LDS (waves 0-3 stage K, waves 4-7 stage V; wave-uniform roles),
// double-buffered with the prefetch issued at the top of the iteration.
// 8 waves/CU = 2 waves/SIMD: the per-tile dependent chain (ds_read K ->
// MFMA -> exp -> ds_write/read P -> MFMA PV) of one wave overlaps the
// other wave's issue slots -- round-3's 1-wave/SIMD exposed-latency fix.
//
// QK^T computed with SWAPPED operands: S = mfma(K,Q) -> D[key][query], so
// each lane holds 4 consecutive keys of one query -> P packed with
// v_cvt_pk_bf16_f32 and stored as one ds_write_b64.
// Out: bf16 [b][4096][64] (n-major).
// -------------------------------------------------------------------------
__global__ __launch_bounds__(512) void flash(
    const unsigned short* Qb, size_t qbat,
    const unsigned short* Kb, size_t krow, size_t kbat,
    const unsigned short* Vb, size_t vrow, size_t vbat,
    unsigned short* __restrict__ Aout, int nkeys)
{
    __shared__ __align__(16) unsigned short Ks[2][32][72];  // [buf][key][ch]   (pad 64->72)
    __shared__ __align__(16) unsigned short Vs[2][64][40];  // [buf][l][key]    (pad 32->40)
    __shared__ __align__(16) unsigned short Ps[8][16][40];  // [wave][query][key] (pad 32->40)

    const int t = threadIdx.x;
    const int wave = t >> 6, lane = t & 63, quad = lane >> 4, lidx = lane & 15;
    const int b = blockIdx.y, q0 = blockIdx.x * 128 + wave * 16;

    const unsigned short* qp = Qb + (size_t)b * qbat;
    const unsigned short* kp = Kb + (size_t)b * kbat;
    const unsigned short* vp = Vb + (size_t)b * vbat;

    // staging roles (wave-uniform): threads 0-255 -> K (32 rows x 8 x 16B);
    // threads 256-511 -> V (64 rows x 4 x 16B)
    const bool stK = t < 256;
    const int krt = t >> 3, kch = (t & 7) * 8;
    const int u = t & 255, vrt = u >> 2, vch = (u & 3) * 8;

    // Q fragments (B-operand of swapped QK): Q[query lidx][ch kh*32+quad*8]
    bf8 qa[2];
    #pragma unroll
    for (int kh = 0; kh < 2; kh++)
        qa[kh] = ldbf8(qp + (size_t)(q0 + lidx) * CINP + kh * 32 + quad * 8);

    f4 O[4];
    float Lp = 0.f;
    #pragma unroll
    for (int lt = 0; lt < 4; lt++) O[lt] = (f4){0.f, 0.f, 0.f, 0.f};

    const int nt = nkeys >> 5;

    // prologue: stage tile 0 into buf 0
    if (stK) *(uint4*)&Ks[0][krt][kch] = *(const uint4*)(kp + (size_t)krt * krow + kch);
    else     *(uint4*)&Vs[0][vrt][vch] = *(const uint4*)(vp + (size_t)vrt * vrow + vch);
    __syncthreads();

    for (int tl = 0; tl < nt; tl++) {
        const int cur = tl & 1;
        const bool pf = (tl + 1 < nt);
        uint4 pre;
        if (pf) {  // issue next-tile global loads early; consumed after compute
            const int m1 = (tl + 1) * 32;
            pre = stK ? *(const uint4*)(kp + (size_t)(m1 + krt) * krow + kch)
                      : *(const uint4*)(vp + (size_t)vrt * vrow + m1 + vch);
        }

        // K frags (A-operand): K[key ms*16+lidx][ch kh*32+quad*8]
        bf8 kf[2][2];
        #pragma unroll
        for (int ms = 0; ms < 2; ms++)
            #pragma unroll
            for (int kh = 0; kh < 2; kh++)
                kf[ms][kh] = *(const bf8*)&Ks[cur][ms * 16 + lidx][kh * 32 + quad * 8];

        // S = K . Q^T : D[key quad*4+r (+ms*16)][query lidx]
        f4 S[2];
        #pragma unroll
        for (int ms = 0; ms < 2; ms++) {
            f4 s = (f4){0.f, 0.f, 0.f, 0.f};
            s = __builtin_amdgcn_mfma_f32_16x16x32_bf16(kf[ms][0], qa[0], s, 0, 0, 0);
            s = __builtin_amdgcn_mfma_f32_16x16x32_bf16(kf[ms][1], qa[1], s, 0, 0, 0);
            S[ms] = s;
        }

        // P = exp(S) (scores bounded ~|50| -> no max subtraction needed);
        // lane holds 4 consecutive keys -> pack & one b64 write per ms
        #pragma unroll
        for (int ms = 0; ms < 2; ms++) {
            float p0 = __expf(S[ms][0]);
            float p1 = __expf(S[ms][1]);
            float p2 = __expf(S[ms][2]);
            float p3 = __expf(S[ms][3]);
            Lp += (p0 + p1) + (p2 + p3);
            uint2 pk;
            pk.x = cvtpk(p0, p1);
            pk.y = cvtpk(p2, p3);
            *(uint2*)&Ps[wave][lidx][ms * 16 + quad * 4] = pk;
        }

        // PV: A = P[query][key], B = V[l][key]
        bf8 pfr = *(const bf8*)&Ps[wave][lidx][quad * 8];
        #pragma unroll
        for (int lt = 0; lt < 4; lt++) {
            bf8 vf = *(const bf8*)&Vs[cur][lt * 16 + lidx][quad * 8];
            O[lt] = __builtin_amdgcn_mfma_f32_16x16x32_bf16(pfr, vf, O[lt], 0, 0, 0);
        }

        if (pf) {  // write prefetched tile into the other buffer
            if (stK) *(uint4*)&Ks[cur ^ 1][krt][kch] = pre;
            else     *(uint4*)&Vs[cur ^ 1][vrt][vch] = pre;
        }
        __syncthreads();
    }

    // ---- normalize & write: L[query] lives at lane lidx=query (cross-quad sum) ----
    float s = Lp;
    s += __shfl_xor(s, 16);
    s += __shfl_xor(s, 32);
    const float inv = 1.f / s;
    #pragma unroll
    for (int r = 0; r < 4; r++) {
        float iv = __shfl(inv, quad * 4 + r);  // query quad*4+r
        size_t n = (size_t)b * HW + q0 + quad * 4 + r;
        #pragma unroll
        for (int lt = 0; lt < 4; lt++)
            Aout[n * LCH + lt * 16 + lidx] = f2bf(O[lt][r] * iv);
    }
}

// -------------------------------------------------------------------------
// conv_o: out[b,o,s] = gamma/8 * sum_c WO[o,c]*LT[s,c] + res[b,o,s]
// LT: bf16 [b][4096][64] with LT[s][c] = lat[c][s] (lat_transpose output).
// Optionally emits ST bf16 [b][s][512] (transposed sa_out for stage-2).
// -------------------------------------------------------------------------
__global__ __launch_bounds__(256) void conv_o(const unsigned short* __restrict__ LT,
                                              const unsigned short* __restrict__ WO,
                                              const float* __restrict__ res,
                                              const float* __restrict__ gamma_p,
                                              float* __restrict__ out,
                                              unsigned short* ST)
{
    const int t = threadIdx.x;
    const int wave = t >> 6, lane = t & 63, quad = lane >> 4, lidx = lane & 15;
    const int b = blockIdx.z, o0 = blockIdx.y * 64;
    const int scol = blockIdx.x * 64 + wave * 16 + lidx;
    const unsigned short* arow = LT + ((size_t)b * HW + scol) * LCH;

    f4 acc[4];
    #pragma unroll
    for (int ot = 0; ot < 4; ot++) acc[ot] = (f4){0.f, 0.f, 0.f, 0.f};

    #pragma unroll
    for (int kh = 0; kh < 2; kh++) {
        bf8 bq = ldbf8(arow + kh * 32 + quad * 8);
        #pragma unroll
        for (int ot = 0; ot < 4; ot++) {
            bf8 af = ldbf8(WO + (size_t)(o0 + ot * 16 + lidx) * LCH + kh * 32 + quad * 8);
            acc[ot] = __builtin_amdgcn_mfma_f32_16x16x32_bf16(af, bq, acc[ot], 0, 0, 0);
        }
    }

    const float scale = gamma_p[0] * 0.125f;  // gamma * 1/sqrt(64)
    #pragma unroll
    for (int ot = 0; ot < 4; ot++) {
        float v[4];
        #pragma unroll
        for (int r = 0; r < 4; r++) {
            size_t idx = ((size_t)b * CINP + o0 + ot * 16 + quad * 4 + r) * HW + scol;
            v[r] = fmaf(scale, acc[ot][r], res[idx]);
            out[idx] = v[r];
        }
        if (ST) {
            union { unsigned short s[4]; uint2 u; } pk;
            #pragma unroll
            for (int r = 0; r < 4; r++) pk.s[r] = f2bf(v[r]);
            *(uint2*)(ST + ((size_t)b * HW + scol) * CINP + o0 + ot * 16 + quad * 4) = pk.u;
        }
    }
}

// -------------------------------------------------------------------------
extern "C" void kernel_launch(void* const* d_in, const int* in_sizes, int n_in,
                              void* d_out, int out_size, void* d_ws, size_t ws_size,
                              hipStream_t stream)
{
    const float* f    = (const float*)d_in[0];
    const float* conc = (const float*)d_in[1];
    const float* wt   = (const float*)d_in[2];
    const float* wp   = (const float*)d_in[3];
    const float* wg   = (const float*)d_in[4];
    const float* wo   = (const float*)d_in[5];
    const float* gsa  = (const float*)d_in[6];
    const float* gmo  = (const float*)d_in[7];
    float* out = (float*)d_out;

    // ws layout (~40.4 MiB):
    //  [0, 32M)   XT bf16 [8][4096][512]; Q/K in place -> later ST + Q2 in place
    //  [32M,36M)  VL bf16 [8][64][4096]  -> later LT (lat transposed)
    //  [36M,40M)  A1/A2 bf16 [8][4096][64] (attention out, n-major)
    //  [40M,...)  WB WO CK CV bf16
    char* ws = (char*)d_ws;
    unsigned short* XT = (unsigned short*)ws;
    unsigned short* VL = (unsigned short*)(ws + ((size_t)32 << 20));
    unsigned short* LT = VL;  // reuse after flash1
    unsigned short* A1 = (unsigned short*)(ws + ((size_t)36 << 20));
    unsigned short* WB = (unsigned short*)(ws + ((size_t)40 << 20));
    unsigned short* WO = WB + 192 * 512;
    unsigned short* CK = WO + 512 * 64;
    unsigned short* CV = CK + 256 * 64;

    dim3 blk256(256), blk512(512);

    precast<<<640, blk256, 0, stream>>>(wt, wp, wg, wo, conc, WB, WO, CK, CV);
    cast_transpose<<<dim3(64, 8, 8), blk256, 0, stream>>>(f, XT);

    // ---- SelfAttention ----
    qkv_gemm<12><<<dim3(64, 8), blk256, 0, stream>>>(XT, WB, VL);
    flash<<<dim3(32, 8), blk512, 0, stream>>>(
        XT, (size_t)HW * CINP,
        XT + 64, CINP, (size_t)HW * CINP,
        VL, HW, (size_t)LCH * HW,
        A1, HW);
    lat_transpose<<<dim3(64, 8), blk256, 0, stream>>>(A1, LT);
    conv_o<<<dim3(64, 8, 8), blk256, 0, stream>>>(LT, WO, f, gsa, out, XT /*emit ST*/);

    // ---- MomentumConceptAttention ----
    qkv_gemm<4><<<dim3(64, 8), blk256, 0, stream>>>(XT /*=ST*/, WB /*wt rows*/, nullptr);
    flash<<<dim3(32, 8), blk512, 0, stream>>>(
        XT, (size_t)HW * CINP,
        CK, LCH, 0,
        CV, 256, 0,
        A1 /*=A2*/, 256);
    lat_transpose<<<dim3(64, 8), blk256, 0, stream>>>(A1, LT);
    conv_o<<<dim3(64, 8, 8), blk256, 0, stream>>>(LT, WO, out, gmo, out, nullptr);
}